// Round 11
// baseline (2868.311 us; speedup 1.0000x reference)
//
#include <hip/hip_runtime.h>
#include <math.h>

typedef unsigned int uint32;
typedef short bf16x8 __attribute__((ext_vector_type(8)));
typedef float f32x4 __attribute__((ext_vector_type(4)));
typedef uint32 u32x2 __attribute__((ext_vector_type(2)));

__device__ __forceinline__ float sigmoidf_(float x){ return 1.0f/(1.0f+expf(-x)); }
__device__ __forceinline__ float softplusf_(float x){ return x>20.0f ? x : log1pf(expf(x)); }
__device__ __forceinline__ int iclampi(int v,int lo,int hi){ return v<lo?lo:(v>hi?hi:v); }

__device__ __forceinline__ float bf2f(uint32 u){ return __uint_as_float(u<<16); }
__device__ __forceinline__ unsigned short f2bf(float f){
  uint32 x = __float_as_uint(f);
  uint32 r = (x + 0x7fffu + ((x>>16)&1u)) >> 16;
  return (unsigned short)r;
}

typedef __attribute__((address_space(1))) const unsigned int ga_u32;
typedef __attribute__((address_space(3))) unsigned int ls_u32;
__device__ __forceinline__ void gl_lds16(const unsigned short* g, unsigned short* l){
  __builtin_amdgcn_global_load_lds((ga_u32*)g, (ls_u32*)l, 16, 0, 0);
}

__device__ __forceinline__ float pe_elem(int s, float vx, float vy, float vz){
  const float F0 = 3.14159265358979f;
  if (s < 3) return s==0?vx:(s==1?vy:vz);
  s -= 3;
  bool isCos = false;
  if (s >= 18){ s -= 18; isCos = true; }
  int fi = s/3, ci = s%3;
  float v = ci==0?vx:(ci==1?vy:vz);
  float f = F0 * (float)(1<<fi);
  return isCos ? cosf(f*v) : sinf(f*v);
}

// ---- transpose+convert (bev/cam features): f32 [C][S] -> bf16 [S][rowStride] ----
__global__ __launch_bounds__(256) void transpose_cb_k(const float* __restrict__ in,
    unsigned short* __restrict__ out, int C, int S, int Cout,
    size_t inStride, size_t outStride, int rowStride)
{
  __shared__ float tile[32][33];
  int b = blockIdx.z;
  int s0 = blockIdx.x*32, c0 = blockIdx.y*32;
  int tx = threadIdx.x & 31, ty = threadIdx.x >> 5;
  #pragma unroll
  for (int i=0;i<32;i+=8){
    int c = c0+ty+i, s = s0+tx;
    tile[ty+i][tx] = (c<C && s<S) ? in[(size_t)b*inStride + (size_t)c*S + s] : 0.0f;
  }
  __syncthreads();
  #pragma unroll
  for (int i=0;i<32;i+=8){
    int s = s0+ty+i, c = c0+tx;
    if (s<S && c<Cout) out[(size_t)b*outStride + (size_t)s*rowStride + c] = f2bf(tile[tx][ty+i]);
  }
}

// ---- ONE kernel for all 12 weight transposes + combined biases ----
__global__ __launch_bounds__(256) void wprep_k(
    const float* __restrict__ g_wz, const float* __restrict__ m_wz,
    const float* __restrict__ g_win, const float* __restrict__ m_win,
    const float* __restrict__ g_w0, const float* __restrict__ m_w0,
    const float* __restrict__ g_w1, const float* __restrict__ m_w1,
    unsigned short* gWmT, unsigned short* mWmT,
    unsigned short* gW0T, unsigned short* mW0T,
    unsigned short* gW1Wz, unsigned short* mW1Wz,
    unsigned short* gW1T2, unsigned short* mW1T2,
    const float* __restrict__ m_b1, const float* __restrict__ m_bz,
    const float* __restrict__ g_b1, const float* __restrict__ g_bz,
    const float* __restrict__ m_bin, const float* __restrict__ g_bin,
    float* __restrict__ CB)
{
  __shared__ float tile[32][33];
  int l = blockIdx.x;
  const float* src; unsigned short* dst;
  int C, Cout, rs, s_t, c_t;
  if (l < 768){ int v=l/384, l2=l%384; s_t=l2%16; c_t=l2/16;
    src = v? m_wz : g_wz; dst = v? mWmT : gWmT; C=768; Cout=768; rs=896; }
  else if (l < 896){ int l0=l-768; int v=l0/64, l2=l0%64; s_t=l2%16; c_t=l2/16;
    src = v? m_win : g_win; dst = (v? mWmT : gWmT) + 768; C=84; Cout=128; rs=896; }
  else if (l < 2432){ int l0=l-896; int v=l0/768, l2=l0%768; int z=l2/256, l3=l2%256; s_t=l3%16; c_t=l3/16;
    src = (v? m_w0 : g_w0) + (size_t)z*512*512; dst = (v? mW0T : gW0T) + (size_t)z*512*512;
    C=512; Cout=512; rs=512; }
  else if (l < 3456){ int l0=l-2432; int v=l0/512, l2=l0%512; int z=l2/256, l3=l2%256; s_t=l3%16; c_t=l3/16;
    src = (v? m_w1 : g_w1) + (size_t)z*512*512; dst = (v? mW1Wz : gW1Wz) + (size_t)z*512*1280;
    C=512; Cout=512; rs=1280; }
  else if (l < 4992){ int l0=l-3456; int v=l0/768, l2=l0%768; int z=l2/384, l3=l2%384; s_t=l3%16; c_t=l3/16;
    src = (v? m_wz : g_wz) + (size_t)(z+1)*768*512; dst = (v? mW1Wz : gW1Wz) + 512 + (size_t)z*512*1280;
    C=768; Cout=768; rs=1280; }
  else if (l < 5504){ int l0=l-4992; int v=l0/256, l2=l0%256; s_t=l2%16; c_t=l2/16;
    src = (v? m_w1 : g_w1) + (size_t)2*512*512; dst = v? mW1T2 : gW1T2; C=512; Cout=512; rs=512; }
  else {
    int idx = (l-5504)*256 + threadIdx.x;
    if (idx < 3072){
      int w = idx >> 9, n = idx & 511;
      float v;
      if (w < 4){
        const float* b1 = (w < 2) ? m_b1 : g_b1;
        const float* bz = (w < 2) ? m_bz : g_bz;
        int i = w & 1;
        v = b1[i*512 + n] + bz[(i+1)*512 + n];
      } else if (w == 4) v = m_bin[n] + m_bz[n];
      else               v = g_bin[n] + g_bz[n];
      CB[idx] = v;
    }
    return;
  }
  int s0 = s_t*32, c0 = c_t*32;
  int tx = threadIdx.x & 31, ty = threadIdx.x >> 5;
  #pragma unroll
  for (int i=0;i<32;i+=8){
    int c = c0+ty+i, s = s0+tx;
    tile[ty+i][tx] = (c<C) ? src[(size_t)c*512 + s] : 0.0f;
  }
  __syncthreads();
  #pragma unroll
  for (int i=0;i<32;i+=8){
    int s = s0+ty+i, c = c0+tx;
    if (c<Cout) dst[(size_t)s*rs + c] = f2bf(tile[tx][ty+i]);
  }
}

// ---------------- per-ray setup (threads >=1200 zero ACC) ----------------
__global__ void setup_rays_k(const int* __restrict__ pix, const float* __restrict__ sK_all,
                             const float* __restrict__ s2in_all,
                             float* __restrict__ dirs, float* __restrict__ vd,
                             float* __restrict__ vdl, float* __restrict__ acc)
{
  int r = blockIdx.x*blockDim.x + threadIdx.x;
  if (r >= 1200){ int z = r - 1200; if (z < 64) acc[z] = 0.0f; return; }
  int cam = r / 200;
  const float* sK = sK_all + cam*16;
  const float* s2in = s2in_all + cam*16;
  float a=sK[0],b=sK[1],c=sK[2],d=sK[4],e=sK[5],f=sK[6],g=sK[8],h=sK[9],i=sK[10];
  float det = a*(e*i-f*h) - b*(d*i-f*g) + c*(d*h-e*g);
  float inv00=(e*i-f*h)/det, inv01=(c*h-b*i)/det, inv02=(b*f-c*e)/det;
  float inv10=(f*g-d*i)/det, inv11=(a*i-c*g)/det, inv12=(c*d-a*f)/det;
  float inv20=(d*h-e*g)/det, inv21=(b*g-a*h)/det, inv22=(a*e-b*d)/det;
  int idx = pix[r];
  float x = (float)(idx % 400) * 2.0f;
  float y = (float)(idx / 400) * 2.0f;
  float dx = inv00*x + inv01*y + inv02;
  float dy = inv10*x + inv11*y + inv12;
  float dz = inv20*x + inv21*y + inv22;
  dirs[r*3+0]=dx; dirs[r*3+1]=dy; dirs[r*3+2]=dz;
  float n = sqrtf(dx*dx+dy*dy+dz*dz);
  float vx=dx/n, vy=dy/n, vz=dz/n;
  vd[r*3+0]=vx; vd[r*3+1]=vy; vd[r*3+2]=vz;
  vdl[r*3+0]=s2in[0]*vx + s2in[1]*vy + s2in[2]*vz;
  vdl[r*3+1]=s2in[4]*vx + s2in[5]*vy + s2in[6]*vz;
  vdl[r*3+2]=s2in[8]*vx + s2in[9]*vy + s2in[10]*vz;
}

// ---- point eval: 2 points per 256-thread block (128 threads each) ----
__global__ __launch_bounds__(256) void eval2_k(
    const unsigned short* __restrict__ camT,
    const unsigned short* __restrict__ bevT,
    const float* __restrict__ dirs, const float* __restrict__ vd, const float* __restrict__ vdl,
    const float* __restrict__ dall, int ndepth, int R0, int P,
    const float* __restrict__ s2in_all, const float* __restrict__ l2c_all, const float* __restrict__ rK_all,
    unsigned short* __restrict__ cat, float* __restrict__ vf)
{
  int grp = threadIdx.x >> 7;
  int tl  = threadIdx.x & 127;
  int p = blockIdx.x*2 + grp;
  if (p >= P) return;
  int rl = p / ndepth;
  int j  = p - rl*ndepth;
  int R  = R0 + rl;
  int cam = R / 200;
  const float* s2in = s2in_all + cam*16;
  const float* l2c  = l2c_all + cam*16;
  const float* rK   = rK_all + cam*16;
  float dx = dirs[R*3+0], dy = dirs[R*3+1], dz = dirs[R*3+2];
  float d = dall ? dall[(size_t)rl*ndepth + j] : (((float)j + 0.5f)/32.0f)*100.0f;
  float px = dx*d, py = dy*d, pz = dz*d;
  float lx = s2in[0]*px + s2in[1]*py + s2in[2]*pz + s2in[3];
  float ly = s2in[4]*px + s2in[5]*py + s2in[6]*pz + s2in[7];
  float lz = s2in[8]*px + s2in[9]*py + s2in[10]*pz + s2in[11];
  float ccx = l2c[0]*lx + l2c[1]*ly + l2c[2]*lz + l2c[3];
  float ccy = l2c[4]*lx + l2c[5]*ly + l2c[6]*lz + l2c[7];
  float ccz = l2c[8]*lx + l2c[9]*ly + l2c[10]*lz + l2c[11];
  float zs = fmaxf(ccz, 0.001f);
  float uu = rK[0]*ccx + rK[1]*ccy + rK[2]*ccz;
  float vv = rK[4]*ccx + rK[5]*ccy + rK[6]*ccz;
  float fu = uu/zs*(100.0f/1600.0f);
  float fv = vv/zs*(56.0f/900.0f);
  bool cvalid = (fu>=0.0f)&&(fu<=99.0f)&&(fv>=0.0f)&&(fv<=55.0f)&&(ccz>0.1f);
  float cfx0 = floorf(fu), cfy0 = floorf(fv);
  int cx0=iclampi((int)cfx0,0,99), cx1=iclampi(cx0+1,0,99);
  int cy0=iclampi((int)cfy0,0,55), cy1=iclampi(cy0+1,0,55);
  float cwx=fu-cfx0, cwy=fv-cfy0;
  float cw00=(1-cwx)*(1-cwy), cw01=cwx*(1-cwy), cw10=(1-cwx)*cwy, cw11=cwx*cwy;
  float bx = (lx+51.2f)/102.4f*199.0f;
  float by = (ly+51.2f)/102.4f*199.0f;
  bool bvalid = (bx>=0.0f)&&(bx<=199.0f)&&(by>=0.0f)&&(by<=199.0f);
  float bfx0=floorf(bx), bfy0=floorf(by);
  int bx0=iclampi((int)bfx0,0,199), bx1=iclampi(bx0+1,0,199);
  int by0=iclampi((int)bfy0,0,199), by1=iclampi(by0+1,0,199);
  float bwx=bx-bfx0, bwy=by-bfy0;
  float bw00=(1-bwx)*(1-bwy), bw01=bwx*(1-bwy), bw10=(1-bwx)*bwy, bw11=bwx*bwy;
  float vflag = (cvalid && bvalid) ? 1.0f : 0.0f;
  uint32* catrow = (uint32*)(cat + (size_t)p*1408);
  auto bil2 = [&](uint32 a, uint32 b, uint32 c, uint32 dd,
                  float w00,float w01,float w10,float w11)->uint32{
    float lo = w00*bf2f(a&0xffffu)+w01*bf2f(b&0xffffu)+w10*bf2f(c&0xffffu)+w11*bf2f(dd&0xffffu);
    float hi = w00*bf2f(a>>16)+w01*bf2f(b>>16)+w10*bf2f(c>>16)+w11*bf2f(dd>>16);
    lo *= vflag; hi *= vflag;
    return (uint32)f2bf(lo) | ((uint32)f2bf(hi)<<16);
  };
  {
    size_t sb00 = (size_t)(by0*200+bx0)*512, sb01 = (size_t)(by0*200+bx1)*512;
    size_t sb10 = (size_t)(by1*200+bx0)*512, sb11 = (size_t)(by1*200+bx1)*512;
    u32x2 u00 = ((const u32x2*)(bevT + sb00))[tl];
    u32x2 u01 = ((const u32x2*)(bevT + sb01))[tl];
    u32x2 u10 = ((const u32x2*)(bevT + sb10))[tl];
    u32x2 u11 = ((const u32x2*)(bevT + sb11))[tl];
    u32x2 res;
    res[0] = bil2(u00[0],u01[0],u10[0],u11[0], bw00,bw01,bw10,bw11);
    res[1] = bil2(u00[1],u01[1],u10[1],u11[1], bw00,bw01,bw10,bw11);
    ((u32x2*)catrow)[128 + tl] = res;
  }
  {
    const unsigned short* cfT = camT + (size_t)cam*5600*256;
    size_t sc00 = (size_t)(cy0*100+cx0)*256, sc01 = (size_t)(cy0*100+cx1)*256;
    size_t sc10 = (size_t)(cy1*100+cx0)*256, sc11 = (size_t)(cy1*100+cx1)*256;
    uint32 u00 = ((const uint32*)(cfT + sc00))[tl];
    uint32 u01 = ((const uint32*)(cfT + sc01))[tl];
    uint32 u10 = ((const uint32*)(cfT + sc10))[tl];
    uint32 u11 = ((const uint32*)(cfT + sc11))[tl];
    catrow[512 + tl] = bil2(u00,u01,u10,u11, cw00,cw01,cw10,cw11);
  }
  if (tl < 64){
    float plx = lx/51.2f, ply = ly/51.2f, plz = (lz+1.0f)/4.0f;
    float pcx = px/100.0f, pcy = py/100.0f, pcz = pz/100.0f;
    float vx=vd[R*3], vy=vd[R*3+1], vz=vd[R*3+2];
    float wx=vdl[R*3], wy=vdl[R*3+1], wz=vdl[R*3+2];
    auto featv = [&](int s)->float{
      if (s >= 84) return 0.0f;
      if (s < 39)  return pe_elem(s, plx, ply, plz);
      if (s < 42)  return (s==39)?wx:((s==40)?wy:wz);
      if (s < 81)  return pe_elem(s-42, pcx, pcy, pcz);
      return (s==81)?vx:((s==82)?vy:vz);
    };
    float v0 = featv(2*tl), v1 = featv(2*tl+1);
    catrow[640 + tl] = (uint32)f2bf(v0) | ((uint32)f2bf(v1)<<16);
  }
  if (vf && tl==0) vf[p] = vflag;
}

// ---------------- 4-wave 128x128 MFMA GEMM, B-direct-to-register ----------------
// LDS-BW was the binding constraint (17.5% MfmaUtil invariant r5-r9; model:
// 96KB LDS/K-step vs 160cy MFMA -> ~21% ceiling). B (weights, L2-resident per
// XCD) now loads global->VGPR directly: LDS traffic/K-step 96KB -> 48KB.
// A-only LDS dbuf (32KB); B register-double-buffered (named sets, static idx).
// Each STAGE_A+LOADB issue is covered by one full K-step of compute.
#define GBM 128
#define GBN 128
#define GBK 64
template<int ACC, int RELU_OUT, int WRITE_XR>
__global__ __launch_bounds__(256) void mgemm_k(
    const unsigned short* __restrict__ A, int lda,
    const unsigned short* __restrict__ BT,
    const float* __restrict__ bias,
    unsigned short* __restrict__ C, int ldc,
    unsigned short* __restrict__ XR,
    int M, int N, int K)
{
  __shared__ unsigned short As[2][GBM*GBK];   // 2 x 16 KB
  int w = blockIdx.x;
  int xcd = w & 7, ii = w >> 3;
  int colp = ii & 3, rgrp = ii >> 2;
  int rowp = rgrp*8 + xcd;
  int row0 = rowp*GBM, col0 = colp*GBN;
  if (row0 >= M) return;
  int tid = threadIdx.x;
  int lane = tid & 63, wave = tid >> 6;
  int wm = wave >> 1, wn = wave & 1;
  int l15 = lane & 15, l4 = lane >> 4;
  int lrow = lane >> 3;
  int lch  = lane & 7;
  int chsw = (lch ^ lrow) * 8;
  const unsigned short* aptr = A  + (size_t)(row0 + wave*32 + lrow)*lda + chsw;
  const unsigned short* bpl  = BT + (size_t)(col0 + wn*64 + l15)*K + l4*8;
  int woff = (wave*32)*64;

  auto STAGEA = [&](int buf, int kk){
    unsigned short* ab = &As[buf][0] + woff;
    #pragma unroll
    for (int i=0;i<4;++i) gl_lds16(aptr + (size_t)i*8*lda + kk, ab + i*8*64);
  };
  bf16x8 bA[8], bB[8];
  auto LOADB = [&](bf16x8* br, int kk){
    #pragma unroll
    for (int nj=0;nj<4;++nj)
      #pragma unroll
      for (int ks=0;ks<2;++ks)
        br[nj*2+ks] = *(const bf16x8*)(bpl + (size_t)nj*16*K + kk + ks*32);
  };

  f32x4 acc[4][4];
  #pragma unroll
  for (int mi=0;mi<4;++mi)
    #pragma unroll
    for (int nj=0;nj<4;++nj){ f32x4 z = {0.f,0.f,0.f,0.f}; acc[mi][nj] = z; }

  auto COMPUTE = [&](const unsigned short* Ab, const bf16x8* br){
    #pragma unroll
    for (int ks=0; ks<2; ++ks){
      bf16x8 a[4];
      #pragma unroll
      for (int mi=0;mi<4;++mi){
        int row = wm*64 + mi*16 + l15;
        int sc = (ks*4 + l4) ^ (row&7);
        a[mi] = *(const bf16x8*)&Ab[row*64 + sc*8];
      }
      #pragma unroll
      for (int mi=0;mi<4;++mi)
        #pragma unroll
        for (int nj=0;nj<4;++nj)
          acc[mi][nj] = __builtin_amdgcn_mfma_f32_16x16x32_bf16(a[mi], br[nj*2+ks], acc[mi][nj], 0,0,0);
    }
  };

  int nk = K / GBK;                     // 8 / 14 / 20 — always even
  STAGEA(0, 0);
  LOADB(bA, 0);
  for (int t=0; t<nk; t+=2){
    __syncthreads();                    // tile t (LDS buf0 + bA) ready
    STAGEA(1, (t+1)*GBK);               // prefetch t+1, hidden under COMPUTE(t)
    LOADB(bB, (t+1)*GBK);
    COMPUTE(&As[0][0], bA);
    __syncthreads();                    // tile t+1 ready; buf0 reads done
    if (t+2 < nk){ STAGEA(0, (t+2)*GBK); LOADB(bA, (t+2)*GBK); }
    COMPUTE(&As[1][0], bB);
  }
  #pragma unroll
  for (int mi=0;mi<4;++mi){
    int gr0 = row0 + wm*64 + mi*16 + l4*4;
    #pragma unroll
    for (int nj=0;nj<4;++nj){
      int gc = col0 + wn*64 + nj*16 + l15;
      if (gc >= N) continue;
      float bv = bias[gc];
      #pragma unroll
      for (int i=0;i<4;++i){
        int gr = gr0 + i;
        if (gr >= M) continue;
        float v = acc[mi][nj][i] + bv;
        if (ACC) v += bf2f((uint32)C[(size_t)gr*ldc + gc]);
        if (RELU_OUT) v = fmaxf(v, 0.0f);
        C[(size_t)gr*ldc + gc] = f2bf(v);
        if (WRITE_XR) XR[(size_t)gr*512 + gc] = f2bf(fmaxf(v, 0.0f));
      }
    }
  }
}

static inline int gemm_grid(int M){
  int nrow = (M + GBM - 1)/GBM;
  int nrowp = (nrow + 7) & ~7;
  return nrowp * 4;
}

// ---------------- out layer, wave per row ----------------
__global__ __launch_bounds__(256) void outlayer_w_k(const unsigned short* __restrict__ X,
    const float* __restrict__ W, const float* __restrict__ b, float* __restrict__ O,
    int M, int dout)
{
  int wid = threadIdx.x >> 6, lane = threadIdx.x & 63;
  int row = blockIdx.x*4 + wid;
  if (row >= M) return;
  const unsigned short* xr = X + (size_t)row*512;
  float s[4] = {0,0,0,0};
  for (int k=lane; k<512; k+=64){
    float xv = fmaxf(bf2f((uint32)xr[k]), 0.0f);
    #pragma unroll
    for (int c=0;c<4;++c)
      if (c < dout) s[c] += xv * W[(size_t)k*dout + c];
  }
  #pragma unroll
  for (int c=0;c<4;++c)
    #pragma unroll
    for (int m=32;m;m>>=1) s[c] += __shfl_xor(s[c], m, 64);
  if (lane == 0)
    for (int c=0;c<dout;++c) O[(size_t)row*dout + c] = s[c] + b[c];
}

// ---------------- coarse post, one wave per ray ----------------
__global__ __launch_bounds__(256) void coarse_post_w_k(const float* __restrict__ OUTB,
    float* __restrict__ MU, float* __restrict__ STD, float* __restrict__ DALL,
    int R0, int rn)
{
  int wid = threadIdx.x >> 6, lane = threadIdx.x & 63;
  int rl = blockIdx.x*4 + wid;
  if (rl >= rn) return;
  int R = R0 + rl;
  float v = 0.0f, muv = 0.0f, sdv = 0.0f;
  if (lane < 32){
    float lg = OUTB[((size_t)rl*32 + lane)*2 + 0];
    float sv = OUTB[((size_t)rl*32 + lane)*2 + 1];
    float mx = lg;
    #pragma unroll
    for (int m=1;m<8;m<<=1) mx = fmaxf(mx, __shfl_xor(mx, m, 64));
    float e = expf(lg - mx);
    float se = e;
    #pragma unroll
    for (int m=1;m<8;m<<=1) se += __shfl_xor(se, m, 64);
    float du = ((float)lane + 0.5f)/32.0f*100.0f;
    float wgt = e/se;
    float mp = wgt*du, sp = wgt*sv;
    #pragma unroll
    for (int m=1;m<8;m<<=1){ mp += __shfl_xor(mp, m, 64); sp += __shfl_xor(sp, m, 64); }
    muv = mp; sdv = softplusf_(sp) + 0.1f;
    if ((lane & 7) == 0){
      MU[R*4 + (lane>>3)] = muv;
      STD[R*4 + (lane>>3)] = sdv;
    }
    v = du;
  }
  {
    int g = (lane - 32) >> 3;
    int src = (lane >= 32) ? g*8 : 0;
    float mub = __shfl(muv, src, 64);
    float sdb = __shfl(sdv, src, 64);
    if (lane >= 32){
      int pp = (lane - 32) & 7;
      float off = -2.0f + (4.0f/7.0f)*(float)pp;
      v = fminf(fmaxf(mub + sdb*off, 0.5f), 100.0f);
    }
  }
  int rank = 0;
  for (int i=0;i<64;++i){
    float vi = __shfl(v, i, 64);
    rank += (vi < v) || (vi == v && i < lane);
  }
  DALL[(size_t)rl*64 + rank] = v;
}

__device__ __forceinline__ void bilin_img(const float* __restrict__ img, int H, int W,
                                          float u, float v, float* out3, bool* valid)
{
  *valid = (u>=0.0f)&&(u<=(float)(W-1))&&(v>=0.0f)&&(v<=(float)(H-1));
  float fx0=floorf(u), fy0=floorf(v);
  int x0=iclampi((int)fx0,0,W-1), x1=iclampi(x0+1,0,W-1);
  int y0=iclampi((int)fy0,0,H-1), y1=iclampi(y0+1,0,H-1);
  float wx=u-fx0, wy=v-fy0;
  float w00=(1-wx)*(1-wy), w01=wx*(1-wy), w10=(1-wx)*wy, w11=wx*wy;
  for (int ch=0; ch<3; ++ch){
    const float* p = img + (size_t)ch*H*W;
    out3[ch] = w00*p[y0*W+x0] + w01*p[y0*W+x1] + w10*p[y1*W+x0] + w11*p[y1*W+x1];
  }
}

// ---------------- render + losses, one wave per ray ----------------
__global__ __launch_bounds__(256) void render_loss_w_k(
  const float* __restrict__ OUTB, const float* __restrict__ VF,
  const float* __restrict__ DALL, const float* __restrict__ MU, const float* __restrict__ STD,
  const float* __restrict__ dirs, const int* __restrict__ pix,
  const float* __restrict__ src_imgs, const float* __restrict__ tgt_imgs,
  const float* __restrict__ s2tg_all, const float* __restrict__ sK_all,
  float* __restrict__ acc, int R0, int rn)
{
  int wid = threadIdx.x >> 6, lane = threadIdx.x & 63;
  int rl = blockIdx.x*4 + wid;
  if (rl >= rn) return;
  int R = R0 + rl;
  int cam = R / 200;
  int j = lane;
  float dj = DALL[(size_t)rl*64 + j];
  float delta = (j<63) ? (DALL[(size_t)rl*64 + j + 1] - dj) : 1000.0f;
  f32x4 o = *(const f32x4*)(OUTB + ((size_t)rl*64 + j)*4);
  float vfp = VF[(size_t)rl*64 + j];
  float sg = softplusf_(o[3])*vfp;
  float alpha = 1.0f - expf(-sg*delta);
  float prod = 1.0f - alpha + 1e-10f;
  #pragma unroll
  for (int dstep=1; dstep<64; dstep<<=1){
    float v = __shfl_up(prod, dstep, 64);
    if (lane >= dstep) prod *= v;
  }
  float T = __shfl_up(prod, 1, 64);
  if (lane == 0) T = 1.0f;
  float w = alpha*T;
  float c0 = w*sigmoidf_(o[0]), c1 = w*sigmoidf_(o[1]), c2 = w*sigmoidf_(o[2]);
  float dsum = w*dj, vs = vfp;
  #pragma unroll
  for (int m=32;m;m>>=1){
    c0 += __shfl_xor(c0,m,64); c1 += __shfl_xor(c1,m,64); c2 += __shfl_xor(c2,m,64);
    dsum += __shfl_xor(dsum,m,64); vs += __shfl_xor(vs,m,64);
  }
  float depth = dsum, rvr = vs/64.0f;
  float mu[4], sd[4];
  #pragma unroll
  for (int g=0;g<4;++g){ mu[g]=MU[R*4+g]; sd[g]=STD[R*4+g]; }
  float e[4], mx=-1e30f;
  #pragma unroll
  for (int g=0;g<4;++g){ float dd=dj-mu[g]; e[g]=-dd*dd*0.125f; mx=fmaxf(mx,e[g]); }
  float se=0;
  #pragma unroll
  for (int g=0;g<4;++g){ e[g]=expf(e[g]-mx); se+=e[g]; }
  float rw[4];
  #pragma unroll
  for (int g=0;g<4;++g) rw[g] = e[g]/se*w + 1e-8f;
  float srw[4], srwd[4];
  #pragma unroll
  for (int g=0;g<4;++g){ srw[g]=rw[g]; srwd[g]=rw[g]*dj; }
  #pragma unroll
  for (int m=32;m;m>>=1){
    #pragma unroll
    for (int g=0;g<4;++g){ srw[g]+=__shfl_xor(srw[g],m,64); srwd[g]+=__shfl_xor(srwd[g],m,64); }
  }
  float smean[4];
  #pragma unroll
  for (int g=0;g<4;++g) smean[g]=srwd[g]/srw[g];
  float sv[4];
  #pragma unroll
  for (int g=0;g<4;++g){ float dd=dj-smean[g]; sv[g]=rw[g]*dd*dd; }
  #pragma unroll
  for (int m=32;m;m>>=1){
    #pragma unroll
    for (int g=0;g<4;++g) sv[g]+=__shfl_xor(sv[g],m,64);
  }
  if (lane != 0) return;
  float klsum=0;
  #pragma unroll
  for (int g=0;g<4;++g){
    float var = sv[g]/srw[g];
    float sstd = sqrtf(var + 1e-6f);
    float dm = mu[g]-smean[g];
    klsum += logf(sstd/sd[g]) + (sd[g]*sd[g] + dm*dm)/(2.0f*(var+1e-6f)) - 0.5f;
  }
  float mind=1e30f;
  #pragma unroll
  for (int g=0;g<4;++g) mind = fminf(mind, fabsf(mu[g]-depth));
  const float* si = src_imgs + (size_t)cam*3*300*800;
  const float* ti = tgt_imgs + (size_t)cam*3*300*800;
  const float* s2tg = s2tg_all + cam*16;
  const float* sK = sK_all + cam*16;
  int idx = pix[R];
  float x = (float)(idx % 400) * 2.0f;
  float y = (float)(idx / 400) * 2.0f;
  float csrc[3]; bool sval;
  bilin_img(si, 300, 800, x, y, csrc, &sval);
  if (!sval){ csrc[0]=0; csrc[1]=0; csrc[2]=0; }
  float csum = fabsf(csrc[0]-c0)+fabsf(csrc[1]-c1)+fabsf(csrc[2]-c2);
  float dx=dirs[R*3], dy=dirs[R*3+1], dz=dirs[R*3+2];
  float px=dx*depth, py=dy*depth, pz=dz*depth;
  float tx=s2tg[0]*px+s2tg[1]*py+s2tg[2]*pz+s2tg[3];
  float ty=s2tg[4]*px+s2tg[5]*py+s2tg[6]*pz+s2tg[7];
  float tz=s2tg[8]*px+s2tg[9]*py+s2tg[10]*pz+s2tg[11];
  float zt=fmaxf(tz,0.001f);
  float uu=(sK[0]*tx+sK[1]*ty+sK[2]*tz)/zt;
  float vv=(sK[4]*tx+sK[5]*ty+sK[6]*tz)/zt;
  float pred[3]; bool tval;
  bilin_img(ti, 300, 800, uu, vv, pred, &tval);
  float tvf = tval?1.0f:0.0f;
  pred[0]*=tvf; pred[1]*=tvf; pred[2]*=tvf;
  float mask = (tval && (tz>0.1f) && (depth<30.0f)) ? 1.0f : 0.0f;
  float l1 = (fabsf(pred[0]-csrc[0])+fabsf(pred[1]-csrc[1])+fabsf(pred[2]-csrc[2]))*(1.0f/3.0f);
  float* a = acc + cam*8;
  atomicAdd(&a[0], csum*rvr);
  atomicAdd(&a[1], klsum);
  atomicAdd(&a[2], mind);
  atomicAdd(&a[3], l1*mask);
  atomicAdd(&a[4], mask);
}

__global__ void finalize_k(const float* __restrict__ acc, float* __restrict__ out){
  if (threadIdx.x==0 && blockIdx.x==0){
    float tot = 0.0f;
    for (int c=0;c<6;++c){
      const float* a = acc + c*8;
      float lc  = a[0] / 600.0f;
      float lkl = a[1] / 800.0f;
      float ld  = a[2] / 200.0f;
      float lr  = a[3] / (a[4] + 1e-6f);
      if (lr != lr) lr = 0.0f;
      tot += lc + lkl + 0.01f*ld + lr;
    }
    out[0] = tot / 6.0f;
  }
}

// ---------------- host-side MLP driver ----------------
static void run_mlp5(hipStream_t stream, int M,
   const unsigned short* WmT, const float* CBin,
   const unsigned short* W0T, const float* b0,
   const unsigned short* W1Wz, const float* CB,
   const unsigned short* W1T2, const float* b1,
   const float* wout, const float* bout, int dout,
   unsigned short* CAT, unsigned short* X, unsigned short* XR, float* OUTB)
{
  int g = gemm_grid(M);
  mgemm_k<0,0,1><<<g,256,0,stream>>>(CAT+512, 1408, WmT, CBin, X, 512, XR, M, 512, 896);
  for (int i=0;i<2;++i){
    mgemm_k<0,1,0><<<g,256,0,stream>>>(XR, 512, W0T + (size_t)i*512*512, b0 + i*512, CAT, 1408, nullptr, M, 512, 512);
    mgemm_k<1,0,1><<<g,256,0,stream>>>(CAT, 1408, W1Wz + (size_t)i*512*1280, CB + i*512, X, 512, XR, M, 512, 1280);
  }
  mgemm_k<0,1,0><<<g,256,0,stream>>>(XR, 512, W0T + (size_t)2*512*512, b0 + 2*512, CAT, 1408, nullptr, M, 512, 512);
  mgemm_k<1,0,0><<<g,256,0,stream>>>(CAT, 1408, W1T2, b1 + 2*512, X, 512, nullptr, M, 512, 512);
  outlayer_w_k<<<(M+3)/4, 256, 0, stream>>>(X, wout, bout, OUTB, M, dout);
}

extern "C" void kernel_launch(void* const* d_in, const int* in_sizes, int n_in,
                              void* d_out, int out_size, void* d_ws, size_t ws_size,
                              hipStream_t stream) {
  (void)in_sizes; (void)n_in; (void)out_size;
  const float* cam_feat = (const float*)d_in[0];
  const float* bev_feat = (const float*)d_in[1];
  const float* src_imgs = (const float*)d_in[2];
  const float* tgt_imgs = (const float*)d_in[3];
  const float* rK   = (const float*)d_in[4];
  const float* sK   = (const float*)d_in[5];
  const float* l2c  = (const float*)d_in[6];
  const float* s2in = (const float*)d_in[7];
  const float* s2tg = (const float*)d_in[8];
  const int*   pix  = (const int*)d_in[9];
  const float* mlp_win = (const float*)d_in[10];
  const float* mlp_bin = (const float*)d_in[11];
  const float* mlp_wz  = (const float*)d_in[12];
  const float* mlp_bz  = (const float*)d_in[13];
  const float* mlp_w0  = (const float*)d_in[14];
  const float* mlp_b0  = (const float*)d_in[15];
  const float* mlp_w1  = (const float*)d_in[16];
  const float* mlp_b1  = (const float*)d_in[17];
  const float* mlp_wout= (const float*)d_in[18];
  const float* mlp_bout= (const float*)d_in[19];
  const float* g_win = (const float*)d_in[20];
  const float* g_bin = (const float*)d_in[21];
  const float* g_wz  = (const float*)d_in[22];
  const float* g_bz  = (const float*)d_in[23];
  const float* g_w0  = (const float*)d_in[24];
  const float* g_b0  = (const float*)d_in[25];
  const float* g_w1  = (const float*)d_in[26];
  const float* g_b1  = (const float*)d_in[27];
  const float* g_wout= (const float*)d_in[28];
  const float* g_bout= (const float*)d_in[29];

  char* base = (char*)d_ws;
  size_t off = 0;
  auto alloc = [&](size_t bytes)->char*{
    char* p = base + off;
    off = (off + bytes + 255) & ~(size_t)255;
    return p;
  };
  float* ACC  = (float*)alloc(64*4);
  float* DIR  = (float*)alloc(3600*4);
  float* VD   = (float*)alloc(3600*4);
  float* VDL  = (float*)alloc(3600*4);
  float* MU   = (float*)alloc(4800*4);
  float* STD  = (float*)alloc(4800*4);
  float* CBm  = (float*)alloc(3072*4);
  unsigned short* bevT = (unsigned short*)alloc((size_t)40000*512*2);
  unsigned short* camT = (unsigned short*)alloc((size_t)6*5600*256*2);
  unsigned short* gWmT  = (unsigned short*)alloc((size_t)512*896*2);
  unsigned short* mWmT  = (unsigned short*)alloc((size_t)512*896*2);
  unsigned short* gW0T  = (unsigned short*)alloc((size_t)3*512*512*2);
  unsigned short* mW0T  = (unsigned short*)alloc((size_t)3*512*512*2);
  unsigned short* gW1Wz = (unsigned short*)alloc((size_t)2*512*1280*2);
  unsigned short* mW1Wz = (unsigned short*)alloc((size_t)2*512*1280*2);
  unsigned short* gW1T2 = (unsigned short*)alloc((size_t)512*512*2);
  unsigned short* mW1T2 = (unsigned short*)alloc((size_t)512*512*2);
  size_t fixed = off;
  const size_t perray = 256 + 180224 + 65536 + 65536 + 1024 + 256;
  const size_t SLACK = 512*1024;
  int Rc = 1200;
  {
    size_t need = fixed + (size_t)1200*perray + SLACK + 8192;
    if (need > ws_size){
      size_t avail = (ws_size > fixed + SLACK + 8192) ? (ws_size - fixed - SLACK - 8192) : perray;
      Rc = (int)(avail / perray);
      if (Rc < 4) Rc = 4;
      Rc &= ~3;
      if (Rc > 1200) Rc = 1200;
    }
  }
  float*          DALL = (float*)alloc((size_t)Rc*64*4);
  unsigned short* CAT  = (unsigned short*)alloc((size_t)Rc*64*1408*2);
  unsigned short* X    = (unsigned short*)alloc((size_t)Rc*64*512*2);
  unsigned short* XR   = (unsigned short*)alloc((size_t)Rc*64*512*2);
  float*          OUTB = (float*)alloc((size_t)Rc*64*4*4);
  float*          VF   = (float*)alloc((size_t)Rc*64*4);

  { dim3 g((40000+31)/32, (512+31)/32, 1);
    transpose_cb_k<<<g,256,0,stream>>>(bev_feat, bevT, 512, 40000, 512, 0, 0, 512); }
  { dim3 g((5600+31)/32, (256+31)/32, 6);
    transpose_cb_k<<<g,256,0,stream>>>(cam_feat, camT, 256, 5600, 256, (size_t)256*5600, (size_t)5600*256, 256); }
  wprep_k<<<5516,256,0,stream>>>(
      g_wz, mlp_wz, g_win, mlp_win, g_w0, mlp_w0, g_w1, mlp_w1,
      gWmT, mWmT, gW0T, mW0T, gW1Wz, mW1Wz, gW1T2, mW1T2,
      mlp_b1, mlp_bz, g_b1, g_bz, mlp_bin, g_bin, CBm);

  setup_rays_k<<<5,256,0,stream>>>(pix, sK, s2in, DIR, VD, VDL, ACC);

  for (int R0=0; R0<1200; R0+=Rc){
    int rn = (1200 - R0 < Rc) ? (1200 - R0) : Rc;
    int Pc = rn*32;
    eval2_k<<<(Pc+1)/2,256,0,stream>>>(camT, bevT, DIR, VD, VDL,
        nullptr, 32, R0, Pc, s2in, l2c, rK, CAT, nullptr);
    run_mlp5(stream, Pc, gWmT, CBm+2560, gW0T, g_b0, gW1Wz, CBm+1024,
             gW1T2, g_b1, g_wout, g_bout, 2, CAT, X, XR, OUTB);
    coarse_post_w_k<<<(rn+3)/4,256,0,stream>>>(OUTB, MU, STD, DALL, R0, rn);
    int Pf = rn*64;
    eval2_k<<<(Pf+1)/2,256,0,stream>>>(camT, bevT, DIR, VD, VDL,
        DALL, 64, R0, Pf, s2in, l2c, rK, CAT, VF);
    run_mlp5(stream, Pf, mWmT, CBm+2048, mW0T, mlp_b0, mW1Wz, CBm,
             mW1T2, mlp_b1, mlp_wout, mlp_bout, 4, CAT, X, XR, OUTB);
    render_loss_w_k<<<(rn+3)/4,256,0,stream>>>(OUTB, VF, DALL, MU, STD,
        DIR, pix, src_imgs, tgt_imgs, s2tg, sK, ACC, R0, rn);
  }
  finalize_k<<<1,1,0,stream>>>(ACC, (float*)d_out);
}

// Round 12
// 2039.801 us; speedup vs baseline: 1.4062x; 1.4062x over previous
//
#include <hip/hip_runtime.h>
#include <math.h>

typedef unsigned int uint32;
typedef short bf16x8 __attribute__((ext_vector_type(8)));
typedef float f32x4 __attribute__((ext_vector_type(4)));
typedef uint32 u32x2 __attribute__((ext_vector_type(2)));

__device__ __forceinline__ float sigmoidf_(float x){ return 1.0f/(1.0f+expf(-x)); }
__device__ __forceinline__ float softplusf_(float x){ return x>20.0f ? x : log1pf(expf(x)); }
__device__ __forceinline__ int iclampi(int v,int lo,int hi){ return v<lo?lo:(v>hi?hi:v); }

__device__ __forceinline__ float bf2f(uint32 u){ return __uint_as_float(u<<16); }
__device__ __forceinline__ unsigned short f2bf(float f){
  uint32 x = __float_as_uint(f);
  uint32 r = (x + 0x7fffu + ((x>>16)&1u)) >> 16;
  return (unsigned short)r;
}

typedef __attribute__((address_space(1))) const unsigned int ga_u32;
typedef __attribute__((address_space(3))) unsigned int ls_u32;
__device__ __forceinline__ void gl_lds16(const unsigned short* g, unsigned short* l){
  __builtin_amdgcn_global_load_lds((ga_u32*)g, (ls_u32*)l, 16, 0, 0);
}

__device__ __forceinline__ float pe_elem(int s, float vx, float vy, float vz){
  const float F0 = 3.14159265358979f;
  if (s < 3) return s==0?vx:(s==1?vy:vz);
  s -= 3;
  bool isCos = false;
  if (s >= 18){ s -= 18; isCos = true; }
  int fi = s/3, ci = s%3;
  float v = ci==0?vx:(ci==1?vy:vz);
  float f = F0 * (float)(1<<fi);
  return isCos ? cosf(f*v) : sinf(f*v);
}

// ---- transpose+convert (bev/cam features): f32 [C][S] -> bf16 [S][rowStride] ----
__global__ __launch_bounds__(256) void transpose_cb_k(const float* __restrict__ in,
    unsigned short* __restrict__ out, int C, int S, int Cout,
    size_t inStride, size_t outStride, int rowStride)
{
  __shared__ float tile[32][33];
  int b = blockIdx.z;
  int s0 = blockIdx.x*32, c0 = blockIdx.y*32;
  int tx = threadIdx.x & 31, ty = threadIdx.x >> 5;
  #pragma unroll
  for (int i=0;i<32;i+=8){
    int c = c0+ty+i, s = s0+tx;
    tile[ty+i][tx] = (c<C && s<S) ? in[(size_t)b*inStride + (size_t)c*S + s] : 0.0f;
  }
  __syncthreads();
  #pragma unroll
  for (int i=0;i<32;i+=8){
    int s = s0+ty+i, c = c0+tx;
    if (s<S && c<Cout) out[(size_t)b*outStride + (size_t)s*rowStride + c] = f2bf(tile[tx][ty+i]);
  }
}

// ---- ONE kernel for all 12 weight transposes + combined biases ----
__global__ __launch_bounds__(256) void wprep_k(
    const float* __restrict__ g_wz, const float* __restrict__ m_wz,
    const float* __restrict__ g_win, const float* __restrict__ m_win,
    const float* __restrict__ g_w0, const float* __restrict__ m_w0,
    const float* __restrict__ g_w1, const float* __restrict__ m_w1,
    unsigned short* gWmT, unsigned short* mWmT,
    unsigned short* gW0T, unsigned short* mW0T,
    unsigned short* gW1Wz, unsigned short* mW1Wz,
    unsigned short* gW1T2, unsigned short* mW1T2,
    const float* __restrict__ m_b1, const float* __restrict__ m_bz,
    const float* __restrict__ g_b1, const float* __restrict__ g_bz,
    const float* __restrict__ m_bin, const float* __restrict__ g_bin,
    float* __restrict__ CB)
{
  __shared__ float tile[32][33];
  int l = blockIdx.x;
  const float* src; unsigned short* dst;
  int C, Cout, rs, s_t, c_t;
  if (l < 768){ int v=l/384, l2=l%384; s_t=l2%16; c_t=l2/16;
    src = v? m_wz : g_wz; dst = v? mWmT : gWmT; C=768; Cout=768; rs=896; }
  else if (l < 896){ int l0=l-768; int v=l0/64, l2=l0%64; s_t=l2%16; c_t=l2/16;
    src = v? m_win : g_win; dst = (v? mWmT : gWmT) + 768; C=84; Cout=128; rs=896; }
  else if (l < 2432){ int l0=l-896; int v=l0/768, l2=l0%768; int z=l2/256, l3=l2%256; s_t=l3%16; c_t=l3/16;
    src = (v? m_w0 : g_w0) + (size_t)z*512*512; dst = (v? mW0T : gW0T) + (size_t)z*512*512;
    C=512; Cout=512; rs=512; }
  else if (l < 3456){ int l0=l-2432; int v=l0/512, l2=l0%512; int z=l2/256, l3=l2%256; s_t=l3%16; c_t=l3/16;
    src = (v? m_w1 : g_w1) + (size_t)z*512*512; dst = (v? mW1Wz : gW1Wz) + (size_t)z*512*1280;
    C=512; Cout=512; rs=1280; }
  else if (l < 4992){ int l0=l-3456; int v=l0/768, l2=l0%768; int z=l2/384, l3=l2%384; s_t=l3%16; c_t=l3/16;
    src = (v? m_wz : g_wz) + (size_t)(z+1)*768*512; dst = (v? mW1Wz : gW1Wz) + 512 + (size_t)z*512*1280;
    C=768; Cout=768; rs=1280; }
  else if (l < 5504){ int l0=l-4992; int v=l0/256, l2=l0%256; s_t=l2%16; c_t=l2/16;
    src = (v? m_w1 : g_w1) + (size_t)2*512*512; dst = v? mW1T2 : gW1T2; C=512; Cout=512; rs=512; }
  else {
    int idx = (l-5504)*256 + threadIdx.x;
    if (idx < 3072){
      int w = idx >> 9, n = idx & 511;
      float v;
      if (w < 4){
        const float* b1 = (w < 2) ? m_b1 : g_b1;
        const float* bz = (w < 2) ? m_bz : g_bz;
        int i = w & 1;
        v = b1[i*512 + n] + bz[(i+1)*512 + n];
      } else if (w == 4) v = m_bin[n] + m_bz[n];
      else               v = g_bin[n] + g_bz[n];
      CB[idx] = v;
    }
    return;
  }
  int s0 = s_t*32, c0 = c_t*32;
  int tx = threadIdx.x & 31, ty = threadIdx.x >> 5;
  #pragma unroll
  for (int i=0;i<32;i+=8){
    int c = c0+ty+i, s = s0+tx;
    tile[ty+i][tx] = (c<C) ? src[(size_t)c*512 + s] : 0.0f;
  }
  __syncthreads();
  #pragma unroll
  for (int i=0;i<32;i+=8){
    int s = s0+ty+i, c = c0+tx;
    if (c<Cout) dst[(size_t)s*rs + c] = f2bf(tile[tx][ty+i]);
  }
}

// ---------------- per-ray setup (threads >=1200 zero ACC) ----------------
__global__ void setup_rays_k(const int* __restrict__ pix, const float* __restrict__ sK_all,
                             const float* __restrict__ s2in_all,
                             float* __restrict__ dirs, float* __restrict__ vd,
                             float* __restrict__ vdl, float* __restrict__ acc)
{
  int r = blockIdx.x*blockDim.x + threadIdx.x;
  if (r >= 1200){ int z = r - 1200; if (z < 64) acc[z] = 0.0f; return; }
  int cam = r / 200;
  const float* sK = sK_all + cam*16;
  const float* s2in = s2in_all + cam*16;
  float a=sK[0],b=sK[1],c=sK[2],d=sK[4],e=sK[5],f=sK[6],g=sK[8],h=sK[9],i=sK[10];
  float det = a*(e*i-f*h) - b*(d*i-f*g) + c*(d*h-e*g);
  float inv00=(e*i-f*h)/det, inv01=(c*h-b*i)/det, inv02=(b*f-c*e)/det;
  float inv10=(f*g-d*i)/det, inv11=(a*i-c*g)/det, inv12=(c*d-a*f)/det;
  float inv20=(d*h-e*g)/det, inv21=(b*g-a*h)/det, inv22=(a*e-b*d)/det;
  int idx = pix[r];
  float x = (float)(idx % 400) * 2.0f;
  float y = (float)(idx / 400) * 2.0f;
  float dx = inv00*x + inv01*y + inv02;
  float dy = inv10*x + inv11*y + inv12;
  float dz = inv20*x + inv21*y + inv22;
  dirs[r*3+0]=dx; dirs[r*3+1]=dy; dirs[r*3+2]=dz;
  float n = sqrtf(dx*dx+dy*dy+dz*dz);
  float vx=dx/n, vy=dy/n, vz=dz/n;
  vd[r*3+0]=vx; vd[r*3+1]=vy; vd[r*3+2]=vz;
  vdl[r*3+0]=s2in[0]*vx + s2in[1]*vy + s2in[2]*vz;
  vdl[r*3+1]=s2in[4]*vx + s2in[5]*vy + s2in[6]*vz;
  vdl[r*3+2]=s2in[8]*vx + s2in[9]*vy + s2in[10]*vz;
}

// ---- point eval: 2 points per 256-thread block (128 threads each) ----
__global__ __launch_bounds__(256) void eval2_k(
    const unsigned short* __restrict__ camT,
    const unsigned short* __restrict__ bevT,
    const float* __restrict__ dirs, const float* __restrict__ vd, const float* __restrict__ vdl,
    const float* __restrict__ dall, int ndepth, int R0, int P,
    const float* __restrict__ s2in_all, const float* __restrict__ l2c_all, const float* __restrict__ rK_all,
    unsigned short* __restrict__ cat, float* __restrict__ vf)
{
  int grp = threadIdx.x >> 7;
  int tl  = threadIdx.x & 127;
  int p = blockIdx.x*2 + grp;
  if (p >= P) return;
  int rl = p / ndepth;
  int j  = p - rl*ndepth;
  int R  = R0 + rl;
  int cam = R / 200;
  const float* s2in = s2in_all + cam*16;
  const float* l2c  = l2c_all + cam*16;
  const float* rK   = rK_all + cam*16;
  float dx = dirs[R*3+0], dy = dirs[R*3+1], dz = dirs[R*3+2];
  float d = dall ? dall[(size_t)rl*ndepth + j] : (((float)j + 0.5f)/32.0f)*100.0f;
  float px = dx*d, py = dy*d, pz = dz*d;
  float lx = s2in[0]*px + s2in[1]*py + s2in[2]*pz + s2in[3];
  float ly = s2in[4]*px + s2in[5]*py + s2in[6]*pz + s2in[7];
  float lz = s2in[8]*px + s2in[9]*py + s2in[10]*pz + s2in[11];
  float ccx = l2c[0]*lx + l2c[1]*ly + l2c[2]*lz + l2c[3];
  float ccy = l2c[4]*lx + l2c[5]*ly + l2c[6]*lz + l2c[7];
  float ccz = l2c[8]*lx + l2c[9]*ly + l2c[10]*lz + l2c[11];
  float zs = fmaxf(ccz, 0.001f);
  float uu = rK[0]*ccx + rK[1]*ccy + rK[2]*ccz;
  float vv = rK[4]*ccx + rK[5]*ccy + rK[6]*ccz;
  float fu = uu/zs*(100.0f/1600.0f);
  float fv = vv/zs*(56.0f/900.0f);
  bool cvalid = (fu>=0.0f)&&(fu<=99.0f)&&(fv>=0.0f)&&(fv<=55.0f)&&(ccz>0.1f);
  float cfx0 = floorf(fu), cfy0 = floorf(fv);
  int cx0=iclampi((int)cfx0,0,99), cx1=iclampi(cx0+1,0,99);
  int cy0=iclampi((int)cfy0,0,55), cy1=iclampi(cy0+1,0,55);
  float cwx=fu-cfx0, cwy=fv-cfy0;
  float cw00=(1-cwx)*(1-cwy), cw01=cwx*(1-cwy), cw10=(1-cwx)*cwy, cw11=cwx*cwy;
  float bx = (lx+51.2f)/102.4f*199.0f;
  float by = (ly+51.2f)/102.4f*199.0f;
  bool bvalid = (bx>=0.0f)&&(bx<=199.0f)&&(by>=0.0f)&&(by<=199.0f);
  float bfx0=floorf(bx), bfy0=floorf(by);
  int bx0=iclampi((int)bfx0,0,199), bx1=iclampi(bx0+1,0,199);
  int by0=iclampi((int)bfy0,0,199), by1=iclampi(by0+1,0,199);
  float bwx=bx-bfx0, bwy=by-bfy0;
  float bw00=(1-bwx)*(1-bwy), bw01=bwx*(1-bwy), bw10=(1-bwx)*bwy, bw11=bwx*bwy;
  float vflag = (cvalid && bvalid) ? 1.0f : 0.0f;
  uint32* catrow = (uint32*)(cat + (size_t)p*1408);
  auto bil2 = [&](uint32 a, uint32 b, uint32 c, uint32 dd,
                  float w00,float w01,float w10,float w11)->uint32{
    float lo = w00*bf2f(a&0xffffu)+w01*bf2f(b&0xffffu)+w10*bf2f(c&0xffffu)+w11*bf2f(dd&0xffffu);
    float hi = w00*bf2f(a>>16)+w01*bf2f(b>>16)+w10*bf2f(c>>16)+w11*bf2f(dd>>16);
    lo *= vflag; hi *= vflag;
    return (uint32)f2bf(lo) | ((uint32)f2bf(hi)<<16);
  };
  {
    size_t sb00 = (size_t)(by0*200+bx0)*512, sb01 = (size_t)(by0*200+bx1)*512;
    size_t sb10 = (size_t)(by1*200+bx0)*512, sb11 = (size_t)(by1*200+bx1)*512;
    u32x2 u00 = ((const u32x2*)(bevT + sb00))[tl];
    u32x2 u01 = ((const u32x2*)(bevT + sb01))[tl];
    u32x2 u10 = ((const u32x2*)(bevT + sb10))[tl];
    u32x2 u11 = ((const u32x2*)(bevT + sb11))[tl];
    u32x2 res;
    res[0] = bil2(u00[0],u01[0],u10[0],u11[0], bw00,bw01,bw10,bw11);
    res[1] = bil2(u00[1],u01[1],u10[1],u11[1], bw00,bw01,bw10,bw11);
    ((u32x2*)catrow)[128 + tl] = res;
  }
  {
    const unsigned short* cfT = camT + (size_t)cam*5600*256;
    size_t sc00 = (size_t)(cy0*100+cx0)*256, sc01 = (size_t)(cy0*100+cx1)*256;
    size_t sc10 = (size_t)(cy1*100+cx0)*256, sc11 = (size_t)(cy1*100+cx1)*256;
    uint32 u00 = ((const uint32*)(cfT + sc00))[tl];
    uint32 u01 = ((const uint32*)(cfT + sc01))[tl];
    uint32 u10 = ((const uint32*)(cfT + sc10))[tl];
    uint32 u11 = ((const uint32*)(cfT + sc11))[tl];
    catrow[512 + tl] = bil2(u00,u01,u10,u11, cw00,cw01,cw10,cw11);
  }
  if (tl < 64){
    float plx = lx/51.2f, ply = ly/51.2f, plz = (lz+1.0f)/4.0f;
    float pcx = px/100.0f, pcy = py/100.0f, pcz = pz/100.0f;
    float vx=vd[R*3], vy=vd[R*3+1], vz=vd[R*3+2];
    float wx=vdl[R*3], wy=vdl[R*3+1], wz=vdl[R*3+2];
    auto featv = [&](int s)->float{
      if (s >= 84) return 0.0f;
      if (s < 39)  return pe_elem(s, plx, ply, plz);
      if (s < 42)  return (s==39)?wx:((s==40)?wy:wz);
      if (s < 81)  return pe_elem(s-42, pcx, pcy, pcz);
      return (s==81)?vx:((s==82)?vy:vz);
    };
    float v0 = featv(2*tl), v1 = featv(2*tl+1);
    catrow[640 + tl] = (uint32)f2bf(v0) | ((uint32)f2bf(v1)<<16);
  }
  if (vf && tl==0) vf[p] = vflag;
}

// ---------------- 4-wave 128x128 MFMA GEMM, dbuf, XCD-bijective swizzle ----------------
#define GBM 128
#define GBN 128
#define GBK 64
template<int ACC, int RELU_OUT, int WRITE_XR>
__global__ __launch_bounds__(256) void mgemm_k(
    const unsigned short* __restrict__ A, int lda,
    const unsigned short* __restrict__ BT,
    const float* __restrict__ bias,
    unsigned short* __restrict__ C, int ldc,
    unsigned short* __restrict__ XR,
    int M, int N, int K)
{
  __shared__ unsigned short As[2][GBM*GBK];
  __shared__ unsigned short Bs[2][GBN*GBK];
  int w = blockIdx.x;
  int xcd = w & 7, ii = w >> 3;
  int colp = ii & 3, rgrp = ii >> 2;
  int rowp = rgrp*8 + xcd;
  int row0 = rowp*GBM, col0 = colp*GBN;
  if (row0 >= M) return;
  int tid = threadIdx.x;
  int lane = tid & 63, wave = tid >> 6;
  int wm = wave >> 1, wn = wave & 1;
  int l15 = lane & 15, l4 = lane >> 4;
  int lrow = lane >> 3;
  int lch  = lane & 7;
  int chsw = (lch ^ lrow) * 8;
  const unsigned short* aptr = A  + (size_t)(row0 + wave*32 + lrow)*lda + chsw;
  const unsigned short* bptr = BT + (size_t)(col0 + wave*32 + lrow)*K   + chsw;
  int woff = (wave*32)*64;

  auto STAGE = [&](int buf, int kk){
    unsigned short* ab = (buf ? &As[1][0] : &As[0][0]) + woff;
    unsigned short* bb = (buf ? &Bs[1][0] : &Bs[0][0]) + woff;
    #pragma unroll
    for (int i=0;i<4;++i) gl_lds16(aptr + (size_t)i*8*lda + kk, ab + i*8*64);
    #pragma unroll
    for (int i=0;i<4;++i) gl_lds16(bptr + (size_t)i*8*K   + kk, bb + i*8*64);
  };

  f32x4 acc[4][4];
  #pragma unroll
  for (int mi=0;mi<4;++mi)
    #pragma unroll
    for (int nj=0;nj<4;++nj){ f32x4 z = {0.f,0.f,0.f,0.f}; acc[mi][nj] = z; }

  STAGE(0, 0);
  int nk = K / GBK;
  for (int t=0; t<nk; ++t){
    __syncthreads();
    if (t+1 < nk) STAGE((t+1)&1, (t+1)*GBK);
    const unsigned short* Ab = (t&1) ? &As[1][0] : &As[0][0];
    const unsigned short* Bb = (t&1) ? &Bs[1][0] : &Bs[0][0];
    #pragma unroll
    for (int ks=0; ks<2; ++ks){
      bf16x8 a[4], b[4];
      #pragma unroll
      for (int mi=0;mi<4;++mi){
        int row = wm*64 + mi*16 + l15;
        int sc = (ks*4 + l4) ^ (row&7);
        a[mi] = *(const bf16x8*)&Ab[row*64 + sc*8];
      }
      #pragma unroll
      for (int nj=0;nj<4;++nj){
        int colr = wn*64 + nj*16 + l15;
        int sc = (ks*4 + l4) ^ (colr&7);
        b[nj] = *(const bf16x8*)&Bb[colr*64 + sc*8];
      }
      #pragma unroll
      for (int mi=0;mi<4;++mi)
        #pragma unroll
        for (int nj=0;nj<4;++nj)
          acc[mi][nj] = __builtin_amdgcn_mfma_f32_16x16x32_bf16(a[mi], b[nj], acc[mi][nj], 0,0,0);
    }
  }
  #pragma unroll
  for (int mi=0;mi<4;++mi){
    int gr0 = row0 + wm*64 + mi*16 + l4*4;
    #pragma unroll
    for (int nj=0;nj<4;++nj){
      int gc = col0 + wn*64 + nj*16 + l15;
      if (gc >= N) continue;
      float bv = bias[gc];
      #pragma unroll
      for (int i=0;i<4;++i){
        int gr = gr0 + i;
        if (gr >= M) continue;
        float v = acc[mi][nj][i] + bv;
        if (ACC) v += bf2f((uint32)C[(size_t)gr*ldc + gc]);
        if (RELU_OUT) v = fmaxf(v, 0.0f);
        C[(size_t)gr*ldc + gc] = f2bf(v);
        if (WRITE_XR) XR[(size_t)gr*512 + gc] = f2bf(fmaxf(v, 0.0f));
      }
    }
  }
}

static inline int gemm_grid(int M){
  int nrow = (M + GBM - 1)/GBM;
  int nrowp = (nrow + 7) & ~7;
  return nrowp * 4;
}

// ---------------- out layer, wave per row ----------------
__global__ __launch_bounds__(256) void outlayer_w_k(const unsigned short* __restrict__ X,
    const float* __restrict__ W, const float* __restrict__ b, float* __restrict__ O,
    int M, int dout)
{
  int wid = threadIdx.x >> 6, lane = threadIdx.x & 63;
  int row = blockIdx.x*4 + wid;
  if (row >= M) return;
  const unsigned short* xr = X + (size_t)row*512;
  float s[4] = {0,0,0,0};
  for (int k=lane; k<512; k+=64){
    float xv = fmaxf(bf2f((uint32)xr[k]), 0.0f);
    #pragma unroll
    for (int c=0;c<4;++c)
      if (c < dout) s[c] += xv * W[(size_t)k*dout + c];
  }
  #pragma unroll
  for (int c=0;c<4;++c)
    #pragma unroll
    for (int m=32;m;m>>=1) s[c] += __shfl_xor(s[c], m, 64);
  if (lane == 0)
    for (int c=0;c<dout;++c) O[(size_t)row*dout + c] = s[c] + b[c];
}

// ---------------- coarse post, one wave per ray ----------------
__global__ __launch_bounds__(256) void coarse_post_w_k(const float* __restrict__ OUTB,
    float* __restrict__ MU, float* __restrict__ STD, float* __restrict__ DALL,
    int R0, int rn)
{
  int wid = threadIdx.x >> 6, lane = threadIdx.x & 63;
  int rl = blockIdx.x*4 + wid;
  if (rl >= rn) return;
  int R = R0 + rl;
  float v = 0.0f, muv = 0.0f, sdv = 0.0f;
  if (lane < 32){
    float lg = OUTB[((size_t)rl*32 + lane)*2 + 0];
    float sv = OUTB[((size_t)rl*32 + lane)*2 + 1];
    float mx = lg;
    #pragma unroll
    for (int m=1;m<8;m<<=1) mx = fmaxf(mx, __shfl_xor(mx, m, 64));
    float e = expf(lg - mx);
    float se = e;
    #pragma unroll
    for (int m=1;m<8;m<<=1) se += __shfl_xor(se, m, 64);
    float du = ((float)lane + 0.5f)/32.0f*100.0f;
    float wgt = e/se;
    float mp = wgt*du, sp = wgt*sv;
    #pragma unroll
    for (int m=1;m<8;m<<=1){ mp += __shfl_xor(mp, m, 64); sp += __shfl_xor(sp, m, 64); }
    muv = mp; sdv = softplusf_(sp) + 0.1f;
    if ((lane & 7) == 0){
      MU[R*4 + (lane>>3)] = muv;
      STD[R*4 + (lane>>3)] = sdv;
    }
    v = du;
  }
  {
    int g = (lane - 32) >> 3;
    int src = (lane >= 32) ? g*8 : 0;
    float mub = __shfl(muv, src, 64);
    float sdb = __shfl(sdv, src, 64);
    if (lane >= 32){
      int pp = (lane - 32) & 7;
      float off = -2.0f + (4.0f/7.0f)*(float)pp;
      v = fminf(fmaxf(mub + sdb*off, 0.5f), 100.0f);
    }
  }
  int rank = 0;
  for (int i=0;i<64;++i){
    float vi = __shfl(v, i, 64);
    rank += (vi < v) || (vi == v && i < lane);
  }
  DALL[(size_t)rl*64 + rank] = v;
}

__device__ __forceinline__ void bilin_img(const float* __restrict__ img, int H, int W,
                                          float u, float v, float* out3, bool* valid)
{
  *valid = (u>=0.0f)&&(u<=(float)(W-1))&&(v>=0.0f)&&(v<=(float)(H-1));
  float fx0=floorf(u), fy0=floorf(v);
  int x0=iclampi((int)fx0,0,W-1), x1=iclampi(x0+1,0,W-1);
  int y0=iclampi((int)fy0,0,H-1), y1=iclampi(y0+1,0,H-1);
  float wx=u-fx0, wy=v-fy0;
  float w00=(1-wx)*(1-wy), w01=wx*(1-wy), w10=(1-wx)*wy, w11=wx*wy;
  for (int ch=0; ch<3; ++ch){
    const float* p = img + (size_t)ch*H*W;
    out3[ch] = w00*p[y0*W+x0] + w01*p[y0*W+x1] + w10*p[y1*W+x0] + w11*p[y1*W+x1];
  }
}

// ---------------- render + losses, one wave per ray ----------------
__global__ __launch_bounds__(256) void render_loss_w_k(
  const float* __restrict__ OUTB, const float* __restrict__ VF,
  const float* __restrict__ DALL, const float* __restrict__ MU, const float* __restrict__ STD,
  const float* __restrict__ dirs, const int* __restrict__ pix,
  const float* __restrict__ src_imgs, const float* __restrict__ tgt_imgs,
  const float* __restrict__ s2tg_all, const float* __restrict__ sK_all,
  float* __restrict__ acc, int R0, int rn)
{
  int wid = threadIdx.x >> 6, lane = threadIdx.x & 63;
  int rl = blockIdx.x*4 + wid;
  if (rl >= rn) return;
  int R = R0 + rl;
  int cam = R / 200;
  int j = lane;
  float dj = DALL[(size_t)rl*64 + j];
  float delta = (j<63) ? (DALL[(size_t)rl*64 + j + 1] - dj) : 1000.0f;
  f32x4 o = *(const f32x4*)(OUTB + ((size_t)rl*64 + j)*4);
  float vfp = VF[(size_t)rl*64 + j];
  float sg = softplusf_(o[3])*vfp;
  float alpha = 1.0f - expf(-sg*delta);
  float prod = 1.0f - alpha + 1e-10f;
  #pragma unroll
  for (int dstep=1; dstep<64; dstep<<=1){
    float v = __shfl_up(prod, dstep, 64);
    if (lane >= dstep) prod *= v;
  }
  float T = __shfl_up(prod, 1, 64);
  if (lane == 0) T = 1.0f;
  float w = alpha*T;
  float c0 = w*sigmoidf_(o[0]), c1 = w*sigmoidf_(o[1]), c2 = w*sigmoidf_(o[2]);
  float dsum = w*dj, vs = vfp;
  #pragma unroll
  for (int m=32;m;m>>=1){
    c0 += __shfl_xor(c0,m,64); c1 += __shfl_xor(c1,m,64); c2 += __shfl_xor(c2,m,64);
    dsum += __shfl_xor(dsum,m,64); vs += __shfl_xor(vs,m,64);
  }
  float depth = dsum, rvr = vs/64.0f;
  float mu[4], sd[4];
  #pragma unroll
  for (int g=0;g<4;++g){ mu[g]=MU[R*4+g]; sd[g]=STD[R*4+g]; }
  float e[4], mx=-1e30f;
  #pragma unroll
  for (int g=0;g<4;++g){ float dd=dj-mu[g]; e[g]=-dd*dd*0.125f; mx=fmaxf(mx,e[g]); }
  float se=0;
  #pragma unroll
  for (int g=0;g<4;++g){ e[g]=expf(e[g]-mx); se+=e[g]; }
  float rw[4];
  #pragma unroll
  for (int g=0;g<4;++g) rw[g] = e[g]/se*w + 1e-8f;
  float srw[4], srwd[4];
  #pragma unroll
  for (int g=0;g<4;++g){ srw[g]=rw[g]; srwd[g]=rw[g]*dj; }
  #pragma unroll
  for (int m=32;m;m>>=1){
    #pragma unroll
    for (int g=0;g<4;++g){ srw[g]+=__shfl_xor(srw[g],m,64); srwd[g]+=__shfl_xor(srwd[g],m,64); }
  }
  float smean[4];
  #pragma unroll
  for (int g=0;g<4;++g) smean[g]=srwd[g]/srw[g];
  float sv[4];
  #pragma unroll
  for (int g=0;g<4;++g){ float dd=dj-smean[g]; sv[g]=rw[g]*dd*dd; }
  #pragma unroll
  for (int m=32;m;m>>=1){
    #pragma unroll
    for (int g=0;g<4;++g) sv[g]+=__shfl_xor(sv[g],m,64);
  }
  if (lane != 0) return;
  float klsum=0;
  #pragma unroll
  for (int g=0;g<4;++g){
    float var = sv[g]/srw[g];
    float sstd = sqrtf(var + 1e-6f);
    float dm = mu[g]-smean[g];
    klsum += logf(sstd/sd[g]) + (sd[g]*sd[g] + dm*dm)/(2.0f*(var+1e-6f)) - 0.5f;
  }
  float mind=1e30f;
  #pragma unroll
  for (int g=0;g<4;++g) mind = fminf(mind, fabsf(mu[g]-depth));
  const float* si = src_imgs + (size_t)cam*3*300*800;
  const float* ti = tgt_imgs + (size_t)cam*3*300*800;
  const float* s2tg = s2tg_all + cam*16;
  const float* sK = sK_all + cam*16;
  int idx = pix[R];
  float x = (float)(idx % 400) * 2.0f;
  float y = (float)(idx / 400) * 2.0f;
  float csrc[3]; bool sval;
  bilin_img(si, 300, 800, x, y, csrc, &sval);
  if (!sval){ csrc[0]=0; csrc[1]=0; csrc[2]=0; }
  float csum = fabsf(csrc[0]-c0)+fabsf(csrc[1]-c1)+fabsf(csrc[2]-c2);
  float dx=dirs[R*3], dy=dirs[R*3+1], dz=dirs[R*3+2];
  float px=dx*depth, py=dy*depth, pz=dz*depth;
  float tx=s2tg[0]*px+s2tg[1]*py+s2tg[2]*pz+s2tg[3];
  float ty=s2tg[4]*px+s2tg[5]*py+s2tg[6]*pz+s2tg[7];
  float tz=s2tg[8]*px+s2tg[9]*py+s2tg[10]*pz+s2tg[11];
  float zt=fmaxf(tz,0.001f);
  float uu=(sK[0]*tx+sK[1]*ty+sK[2]*tz)/zt;
  float vv=(sK[4]*tx+sK[5]*ty+sK[6]*tz)/zt;
  float pred[3]; bool tval;
  bilin_img(ti, 300, 800, uu, vv, pred, &tval);
  float tvf = tval?1.0f:0.0f;
  pred[0]*=tvf; pred[1]*=tvf; pred[2]*=tvf;
  float mask = (tval && (tz>0.1f) && (depth<30.0f)) ? 1.0f : 0.0f;
  float l1 = (fabsf(pred[0]-csrc[0])+fabsf(pred[1]-csrc[1])+fabsf(pred[2]-csrc[2]))*(1.0f/3.0f);
  float* a = acc + cam*8;
  atomicAdd(&a[0], csum*rvr);
  atomicAdd(&a[1], klsum);
  atomicAdd(&a[2], mind);
  atomicAdd(&a[3], l1*mask);
  atomicAdd(&a[4], mask);
}

__global__ void finalize_k(const float* __restrict__ acc, float* __restrict__ out){
  if (threadIdx.x==0 && blockIdx.x==0){
    float tot = 0.0f;
    for (int c=0;c<6;++c){
      const float* a = acc + c*8;
      float lc  = a[0] / 600.0f;
      float lkl = a[1] / 800.0f;
      float ld  = a[2] / 200.0f;
      float lr  = a[3] / (a[4] + 1e-6f);
      if (lr != lr) lr = 0.0f;
      tot += lc + lkl + 0.01f*ld + lr;
    }
    out[0] = tot / 6.0f;
  }
}

// ---------------- host-side MLP driver ----------------
static void run_mlp5(hipStream_t stream, int M,
   const unsigned short* WmT, const float* CBin,
   const unsigned short* W0T, const float* b0,
   const unsigned short* W1Wz, const float* CB,
   const unsigned short* W1T2, const float* b1,
   const float* wout, const float* bout, int dout,
   unsigned short* CAT, unsigned short* X, unsigned short* XR, float* OUTB)
{
  int g = gemm_grid(M);
  mgemm_k<0,0,1><<<g,256,0,stream>>>(CAT+512, 1408, WmT, CBin, X, 512, XR, M, 512, 896);
  for (int i=0;i<2;++i){
    mgemm_k<0,1,0><<<g,256,0,stream>>>(XR, 512, W0T + (size_t)i*512*512, b0 + i*512, CAT, 1408, nullptr, M, 512, 512);
    mgemm_k<1,0,1><<<g,256,0,stream>>>(CAT, 1408, W1Wz + (size_t)i*512*1280, CB + i*512, X, 512, XR, M, 512, 1280);
  }
  mgemm_k<0,1,0><<<g,256,0,stream>>>(XR, 512, W0T + (size_t)2*512*512, b0 + 2*512, CAT, 1408, nullptr, M, 512, 512);
  mgemm_k<1,0,0><<<g,256,0,stream>>>(CAT, 1408, W1T2, b1 + 2*512, X, 512, nullptr, M, 512, 512);
  outlayer_w_k<<<(M+3)/4, 256, 0, stream>>>(X, wout, bout, OUTB, M, dout);
}

extern "C" void kernel_launch(void* const* d_in, const int* in_sizes, int n_in,
                              void* d_out, int out_size, void* d_ws, size_t ws_size,
                              hipStream_t stream) {
  (void)in_sizes; (void)n_in; (void)out_size;
  const float* cam_feat = (const float*)d_in[0];
  const float* bev_feat = (const float*)d_in[1];
  const float* src_imgs = (const float*)d_in[2];
  const float* tgt_imgs = (const float*)d_in[3];
  const float* rK   = (const float*)d_in[4];
  const float* sK   = (const float*)d_in[5];
  const float* l2c  = (const float*)d_in[6];
  const float* s2in = (const float*)d_in[7];
  const float* s2tg = (const float*)d_in[8];
  const int*   pix  = (const int*)d_in[9];
  const float* mlp_win = (const float*)d_in[10];
  const float* mlp_bin = (const float*)d_in[11];
  const float* mlp_wz  = (const float*)d_in[12];
  const float* mlp_bz  = (const float*)d_in[13];
  const float* mlp_w0  = (const float*)d_in[14];
  const float* mlp_b0  = (const float*)d_in[15];
  const float* mlp_w1  = (const float*)d_in[16];
  const float* mlp_b1  = (const float*)d_in[17];
  const float* mlp_wout= (const float*)d_in[18];
  const float* mlp_bout= (const float*)d_in[19];
  const float* g_win = (const float*)d_in[20];
  const float* g_bin = (const float*)d_in[21];
  const float* g_wz  = (const float*)d_in[22];
  const float* g_bz  = (const float*)d_in[23];
  const float* g_w0  = (const float*)d_in[24];
  const float* g_b0  = (const float*)d_in[25];
  const float* g_w1  = (const float*)d_in[26];
  const float* g_b1  = (const float*)d_in[27];
  const float* g_wout= (const float*)d_in[28];
  const float* g_bout= (const float*)d_in[29];

  char* base = (char*)d_ws;
  size_t off = 0;
  auto alloc = [&](size_t bytes)->char*{
    char* p = base + off;
    off = (off + bytes + 255) & ~(size_t)255;
    return p;
  };
  float* ACC  = (float*)alloc(64*4);
  float* DIR  = (float*)alloc(3600*4);
  float* VD   = (float*)alloc(3600*4);
  float* VDL  = (float*)alloc(3600*4);
  float* MU   = (float*)alloc(4800*4);
  float* STD  = (float*)alloc(4800*4);
  float* CBm  = (float*)alloc(3072*4);
  unsigned short* bevT = (unsigned short*)alloc((size_t)40000*512*2);
  unsigned short* camT = (unsigned short*)alloc((size_t)6*5600*256*2);
  unsigned short* gWmT  = (unsigned short*)alloc((size_t)512*896*2);
  unsigned short* mWmT  = (unsigned short*)alloc((size_t)512*896*2);
  unsigned short* gW0T  = (unsigned short*)alloc((size_t)3*512*512*2);
  unsigned short* mW0T  = (unsigned short*)alloc((size_t)3*512*512*2);
  unsigned short* gW1Wz = (unsigned short*)alloc((size_t)2*512*1280*2);
  unsigned short* mW1Wz = (unsigned short*)alloc((size_t)2*512*1280*2);
  unsigned short* gW1T2 = (unsigned short*)alloc((size_t)512*512*2);
  unsigned short* mW1T2 = (unsigned short*)alloc((size_t)512*512*2);
  size_t fixed = off;
  const size_t perray = 256 + 180224 + 65536 + 65536 + 1024 + 256;
  const size_t SLACK = 512*1024;
  int Rc = 1200;
  {
    size_t need = fixed + (size_t)1200*perray + SLACK + 8192;
    if (need > ws_size){
      size_t avail = (ws_size > fixed + SLACK + 8192) ? (ws_size - fixed - SLACK - 8192) : perray;
      Rc = (int)(avail / perray);
      if (Rc < 4) Rc = 4;
      Rc &= ~3;
      if (Rc > 1200) Rc = 1200;
    }
  }
  float*          DALL = (float*)alloc((size_t)Rc*64*4);
  unsigned short* CAT  = (unsigned short*)alloc((size_t)Rc*64*1408*2);
  unsigned short* X    = (unsigned short*)alloc((size_t)Rc*64*512*2);
  unsigned short* XR   = (unsigned short*)alloc((size_t)Rc*64*512*2);
  float*          OUTB = (float*)alloc((size_t)Rc*64*4*4);
  float*          VF   = (float*)alloc((size_t)Rc*64*4);

  { dim3 g((40000+31)/32, (512+31)/32, 1);
    transpose_cb_k<<<g,256,0,stream>>>(bev_feat, bevT, 512, 40000, 512, 0, 0, 512); }
  { dim3 g((5600+31)/32, (256+31)/32, 6);
    transpose_cb_k<<<g,256,0,stream>>>(cam_feat, camT, 256, 5600, 256, (size_t)256*5600, (size_t)5600*256, 256); }
  wprep_k<<<5516,256,0,stream>>>(
      g_wz, mlp_wz, g_win, mlp_win, g_w0, mlp_w0, g_w1, mlp_w1,
      gWmT, mWmT, gW0T, mW0T, gW1Wz, mW1Wz, gW1T2, mW1T2,
      mlp_b1, mlp_bz, g_b1, g_bz, mlp_bin, g_bin, CBm);

  setup_rays_k<<<5,256,0,stream>>>(pix, sK, s2in, DIR, VD, VDL, ACC);

  for (int R0=0; R0<1200; R0+=Rc){
    int rn = (1200 - R0 < Rc) ? (1200 - R0) : Rc;
    int Pc = rn*32;
    eval2_k<<<(Pc+1)/2,256,0,stream>>>(camT, bevT, DIR, VD, VDL,
        nullptr, 32, R0, Pc, s2in, l2c, rK, CAT, nullptr);
    run_mlp5(stream, Pc, gWmT, CBm+2560, gW0T, g_b0, gW1Wz, CBm+1024,
             gW1T2, g_b1, g_wout, g_bout, 2, CAT, X, XR, OUTB);
    coarse_post_w_k<<<(rn+3)/4,256,0,stream>>>(OUTB, MU, STD, DALL, R0, rn);
    int Pf = rn*64;
    eval2_k<<<(Pf+1)/2,256,0,stream>>>(camT, bevT, DIR, VD, VDL,
        DALL, 64, R0, Pf, s2in, l2c, rK, CAT, VF);
    run_mlp5(stream, Pf, mWmT, CBm+2048, mW0T, mlp_b0, mW1Wz, CBm,
             mW1T2, mlp_b1, mlp_wout, mlp_bout, 4, CAT, X, XR, OUTB);
    render_loss_w_k<<<(rn+3)/4,256,0,stream>>>(OUTB, VF, DALL, MU, STD,
        DIR, pix, src_imgs, tgt_imgs, s2tg, sK, ACC, R0, rn);
  }
  finalize_k<<<1,1,0,stream>>>(ACC, (float*)d_out);
}